// Round 10
// baseline (239.438 us; speedup 1.0000x reference)
//
#include <hip/hip_runtime.h>
#include <cstdint>
#include <cstddef>

// ---------------------------------------------------------------------------
// ASD_RNN round 20: r19 structure with
//  (1) v_bf16 ELIMINATED: GEMM1 + dot read v_feat f32 directly (in-register
//      bf16 conversion); rowstats (n2/gpart) folded into the dot role;
//      k_prep drops the whole v pass (7262 -> 3166 blocks).
//  (2) s_setprio(1) on LSTM-role waves in the persistent kernel (xg-GEMM and
//      dd roles stay prio 0) -- role-split contention fix.
// B=64, S=64, F_IN=2048, H=512, 4H=2048, P2=20.
// ---------------------------------------------------------------------------

typedef __attribute__((ext_vector_type(8))) short short8;
typedef __attribute__((ext_vector_type(4))) float f32x4;
typedef unsigned long long ull;

__device__ __forceinline__ ushort f2bf(float x) {
    uint32_t u = __float_as_uint(x);
    return (ushort)((u + 0x7FFF + ((u >> 16) & 1)) >> 16);   // RNE
}
__device__ __forceinline__ float bf2f(ushort u) {
    return __uint_as_float(((uint32_t)u) << 16);
}
__device__ __forceinline__ float sigm(float x) { return 1.f / (1.f + expf(-x)); }
__device__ __forceinline__ float tanh_fast(float x) { return 2.f / (1.f + expf(-2.f * x)) - 1.f; }

// ---------------------------------------------------------------------------
// k_prep: weight/proto pre-processing + workspace zeroing (no v_feat pass).
//   [0,40)        proto convert
//   [40,52)       proto pad rows 20..31
//   [52,60)       bias remap
//   [60,3132)     transposes (W_enc / Wx / Wh)
//   [3132]        p2 + dd_done zero
//   [3133,3165)   hbuf slot 0 zero
//   [3165]        flags + xgf zero
// ---------------------------------------------------------------------------
__global__ __launch_bounds__(256) void k_prep(
    const float* __restrict__ proto,
    const float* __restrict__ bx, const float* __restrict__ bh,
    const float* __restrict__ W_enc, const float* __restrict__ Wx,
    const float* __restrict__ Wh,
    ushort* __restrict__ proto_bf,
    float* __restrict__ bxh, ushort* __restrict__ Wenc_t,
    ushort* __restrict__ Wx_t, ushort* __restrict__ Whr,
    float* __restrict__ p2,
    ushort* __restrict__ hbuf, int* __restrict__ flags, int* __restrict__ dd_done,
    int* __restrict__ xgf)
{
    __shared__ float ts[32][33];
    const int blk = blockIdx.x;
    const int tid = threadIdx.x;

    if (blk < 40) {                                 // proto convert
        int i = blk * 256 + tid;
        float4 v = ((const float4*)proto)[i];
        ushort4 o;
        o.x = f2bf(v.x); o.y = f2bf(v.y); o.z = f2bf(v.z); o.w = f2bf(v.w);
        ((ushort4*)proto_bf)[i] = o;
    } else if (blk < 52) {                          // proto pad rows 20..31
        int row = 20 + (blk - 40);
        ushort4 z = {0, 0, 0, 0};
        ((ushort4*)(proto_bf + (size_t)row * 2048))[tid * 2] = z;
        ((ushort4*)(proto_bf + (size_t)row * 2048))[tid * 2 + 1] = z;
    } else if (blk < 60) {                          // bias remap
        int n = (blk - 52) * 256 + tid;
        int np = ((n & 511) << 2) | (n >> 9);
        bxh[np] = bx[n] + bh[n];
    } else if (blk < 3132) {                        // transposes
        const float* in;
        ushort* outp;
        int R, C, remap, t;
        if (blk < 1084)      { in = W_enc; outp = Wenc_t; R = 2048; C = 512;  remap = 0; t = blk - 60; }
        else if (blk < 2108) { in = Wx;    outp = Wx_t;   R = 512;  C = 2048; remap = 1; t = blk - 1084; }
        else                 { in = Wh;    outp = Whr;    R = 512;  C = 2048; remap = 1; t = blk - 2108; }
        int tpr = C / 32;
        int cx = t % tpr, cy = t / tpr;
        int r0 = cy * 32, c0 = cx * 32;
        int rr = tid >> 3, cc = (tid & 7) * 4;
        float4 v = *(const float4*)(in + (size_t)(r0 + rr) * C + c0 + cc);
        ts[rr][cc + 0] = v.x; ts[rr][cc + 1] = v.y; ts[rr][cc + 2] = v.z; ts[rr][cc + 3] = v.w;
        __syncthreads();
        ushort4 o;
        o.x = f2bf(ts[cc + 0][rr]);
        o.y = f2bf(ts[cc + 1][rr]);
        o.z = f2bf(ts[cc + 2][rr]);
        o.w = f2bf(ts[cc + 3][rr]);
        int n = c0 + rr;
        int np = remap ? (((n & 511) << 2) | (n >> 9)) : n;
        *(ushort4*)(outp + (size_t)np * R + r0 + cc) = o;
    } else if (blk == 3132) {                       // p2 + dd_done zero
        const int lane = tid & 63, w = tid >> 6;
        for (int p = w; p < 20; p += 4) {
            const float* pr = proto + (size_t)p * 2048;
            float a = 0.f;
#pragma unroll
            for (int i = 0; i < 8; ++i) {
                float4 x = ((const float4*)pr)[i * 64 + lane];
                a += x.x * x.x + x.y * x.y + x.z * x.z + x.w * x.w;
            }
#pragma unroll
            for (int o = 32; o > 0; o >>= 1) a += __shfl_down(a, o);
            if (lane == 0) p2[p] = a;
        }
        if (tid == 0) *dd_done = 0;
    } else if (blk < 3165) {                        // hbuf slot 0 zero
        ((ull*)hbuf)[(blk - 3133) * 256 + tid] = 0ULL;
    } else {                                        // flags + xgf zero
        for (int i = tid; i < 2048; i += 256) flags[i] = 0;
        for (int i = tid; i < 512; i += 256) xgf[i] = 0;
    }
}

// ---------------------------------------------------------------------------
// k_mid: GEMM1 (encoder, 64x128 tiles, blocks 0..255, A from v_feat f32 with
// in-register bf16 conversion) + dot w/ rowstats (blocks 256..319).
// ---------------------------------------------------------------------------
__global__ __launch_bounds__(256) void k_mid(
    const float* __restrict__ v_feat, const ushort* __restrict__ Bt,
    const float* __restrict__ bias0,
    const float* __restrict__ cat_emb, const int* __restrict__ category,
    ushort* __restrict__ C,
    const ushort* __restrict__ proto_bf, float* __restrict__ dots,
    const float* __restrict__ W_gate,
    float* __restrict__ n2, float* __restrict__ gpart)
{
    __shared__ ushort As[64][40];
    __shared__ ushort Bs[128][40];
    const int tid = threadIdx.x;
    const int lane = tid & 63, w = tid >> 6;
    const int quad = lane >> 4, l16 = lane & 15;
    const int blk = blockIdx.x;

    if (blk >= 256) {
        // ------- dot + rowstats: rows r0..r0+15 per wave, f32 source -------
        const int r0 = (blk - 256) * 64 + w * 16;
        f32x4 acc[2] = {};
        const float* arow = v_feat + (size_t)(r0 + l16) * 2048 + quad * 8;
        const float* wrow = W_gate + quad * 8;
        const ushort* b0p = proto_bf + (size_t)l16 * 2048 + quad * 8;
        const ushort* b1p = proto_bf + (size_t)(16 + l16) * 2048 + quad * 8;
        float sa = 0.f, sg = 0.f;
#pragma unroll 4
        for (int kk = 0; kk < 64; ++kk) {
            float4 x0 = ((const float4*)(arow + kk * 32))[0];
            float4 x1 = ((const float4*)(arow + kk * 32))[1];
            float4 w0 = ((const float4*)(wrow + kk * 32))[0];
            float4 w1 = ((const float4*)(wrow + kk * 32))[1];
            short8 af;
            af[0] = (short)f2bf(x0.x); af[1] = (short)f2bf(x0.y);
            af[2] = (short)f2bf(x0.z); af[3] = (short)f2bf(x0.w);
            af[4] = (short)f2bf(x1.x); af[5] = (short)f2bf(x1.y);
            af[6] = (short)f2bf(x1.z); af[7] = (short)f2bf(x1.w);
            sa += x0.x * x0.x + x0.y * x0.y + x0.z * x0.z + x0.w * x0.w
                + x1.x * x1.x + x1.y * x1.y + x1.z * x1.z + x1.w * x1.w;
            sg += x0.x * w0.x + x0.y * w0.y + x0.z * w0.z + x0.w * w0.w
                + x1.x * w1.x + x1.y * w1.y + x1.z * w1.z + x1.w * w1.w;
            short8 bf0 = *(const short8*)(b0p + kk * 32);
            short8 bf1 = *(const short8*)(b1p + kk * 32);
            acc[0] = __builtin_amdgcn_mfma_f32_16x16x32_bf16(af, bf0, acc[0], 0, 0, 0);
            acc[1] = __builtin_amdgcn_mfma_f32_16x16x32_bf16(af, bf1, acc[1], 0, 0, 0);
        }
#pragma unroll
        for (int t = 0; t < 2; ++t)
#pragma unroll
            for (int r = 0; r < 4; ++r)
                dots[(size_t)(r0 + quad * 4 + r) * 32 + t * 16 + l16] = acc[t][r];
        sa += __shfl_down(sa, 32); sa += __shfl_down(sa, 16);
        sg += __shfl_down(sg, 32); sg += __shfl_down(sg, 16);
        if (lane < 16) {
            n2[r0 + lane] = sa;
            gpart[r0 + lane] = sg;
        }
        return;
    }

    // ---------------- GEMM1 tile: A from v_feat f32, converted -------------
    const int m0 = (blk >> 2) * 64, n0 = (blk & 3) * 128;
    const int wm = (w & 1) * 32, wn = (w >> 1) * 64;
    const int K = 2048;

    f32x4 acc[2][4] = {};
    const int lr = tid >> 2;
    const int lc = (tid & 3) * 8;

    for (int k0 = 0; k0 < K; k0 += 32) {
        const float* ap = v_feat + (size_t)(m0 + lr) * K + k0 + lc;
        float4 va = ((const float4*)ap)[0];
        float4 vb = ((const float4*)ap)[1];
        uint4 b0 = *(const uint4*)(Bt + (size_t)(n0 + lr) * K + k0 + lc);
        uint4 b1 = *(const uint4*)(Bt + (size_t)(n0 + 64 + lr) * K + k0 + lc);
        ushort4 ca, cb;
        ca.x = f2bf(va.x); ca.y = f2bf(va.y); ca.z = f2bf(va.z); ca.w = f2bf(va.w);
        cb.x = f2bf(vb.x); cb.y = f2bf(vb.y); cb.z = f2bf(vb.z); cb.w = f2bf(vb.w);
        __syncthreads();
        *(ushort4*)&As[lr][lc] = ca;
        *(ushort4*)&As[lr][lc + 4] = cb;
        *(uint4*)&Bs[lr][lc] = b0;
        *(uint4*)&Bs[64 + lr][lc] = b1;
        __syncthreads();
        short8 af[2], bf[4];
#pragma unroll
        for (int i = 0; i < 2; ++i) af[i] = *(const short8*)&As[wm + i * 16 + l16][quad * 8];
#pragma unroll
        for (int j = 0; j < 4; ++j) bf[j] = *(const short8*)&Bs[wn + j * 16 + l16][quad * 8];
#pragma unroll
        for (int i = 0; i < 2; ++i)
#pragma unroll
            for (int j = 0; j < 4; ++j)
                acc[i][j] = __builtin_amdgcn_mfma_f32_16x16x32_bf16(af[i], bf[j], acc[i][j], 0, 0, 0);
    }

#pragma unroll
    for (int i = 0; i < 2; ++i) {
        int mbase = m0 + wm + i * 16 + quad * 4;
#pragma unroll
        for (int r = 0; r < 4; ++r) {
            int m = mbase + r;
            const float* ce = cat_emb + category[m >> 6] * 512;
#pragma unroll
            for (int j = 0; j < 4; ++j) {
                int n = n0 + wn + j * 16 + l16;
                float v = fmaxf(acc[i][j][r] + bias0[n], 0.f) + ce[n];
                C[(size_t)m * 512 + n] = f2bf(v);
            }
        }
    }
}

// ---------------------------------------------------------------------------
// Persistent fused kernel: 384 blocks x 512 threads (r19 structure).
//  blocks 0..63   : LSTM (r16 protocol; xg gated by xgf flags; setprio 1).
//  blocks 64..319 : x-gate GEMM, step-major tiles, two phases per block.
//  blocks 320..383: dd logit for batch (bn-320).
// ---------------------------------------------------------------------------
__global__ __launch_bounds__(512, 2) void k_lstm_persist(
    ushort* __restrict__ xg,             // [s][b][n'] bf16 (written by GEMM2 role)
    const ushort* __restrict__ fuse,     // [b*64+s][512] bf16
    const ushort* __restrict__ Wx_t,     // [n'][512] bf16
    const float* __restrict__ bxh,       // [n'] fp32
    int* __restrict__ xgf,               // [32*16] tile flags
    const ushort* __restrict__ Whr,      // [n'=2048][k=512] bf16
    ushort* __restrict__ hbuf,           // 65 slots x 32768 ushorts (slot0 zero)
    int* __restrict__ flags,             // [64*32] zeroed, line-padded
    const float* __restrict__ W_dec, const float* __restrict__ b_dec,
    const float* __restrict__ b_dd, const float* __restrict__ b_gate,
    const float* __restrict__ dots, const float* __restrict__ n2,
    const float* __restrict__ p2, const float* __restrict__ W_dd,
    const float* __restrict__ gpart,
    float* __restrict__ dd_logit, float* __restrict__ g_logit,
    int* __restrict__ dd_done,
    float* __restrict__ out)
{
    __shared__ __align__(16) ushort hin_s[16 * 520];   // LSTM: 16 rows pad 1040B
    __shared__ __align__(16) ushort hstage[512];
    __shared__ float fred[8][64];
    __shared__ __align__(16) ushort As[128][40];       // GEMM role
    __shared__ __align__(16) ushort Bs[128][40];

    const int tid = threadIdx.x;
    const int lane = tid & 63, wv = tid >> 6;
    const int quad = lane >> 4, l16 = lane & 15;
    const int bn = blockIdx.x;

    if (bn >= 320) {
        // ---------------- dd logit for batch b (dots precomputed) --------
        const int b = bn - 320;
        if (tid < 64) {                              // g_logit reduction
            float gp = gpart[b * 64 + tid];
#pragma unroll
            for (int o = 32; o > 0; o >>= 1) gp += __shfl_down(gp, o);
            if (tid == 0)
                __hip_atomic_store(&g_logit[b], gp, __ATOMIC_RELAXED, __HIP_MEMORY_SCOPE_AGENT);
        }
        float acc = 0.f;
        for (int u = tid; u < 1280; u += 512) {
            int s = u / 20, p = u - s * 20;
            int bs = b * 64 + s;
            float d = n2[bs] - 2.f * dots[(size_t)bs * 32 + p] + p2[p];
            acc += logf((d + 1.0f) / (d + 1e-8f)) * W_dd[s * 20 + p];
        }
#pragma unroll
        for (int o = 32; o > 0; o >>= 1) acc += __shfl_down(acc, o);
        if (lane == 0) fred[wv][0] = acc;
        __syncthreads();
        if (tid == 0) {
            float t = 0.f;
#pragma unroll
            for (int p = 0; p < 8; ++p) t += fred[p][0];
            __hip_atomic_store(&dd_logit[b], t, __ATOMIC_RELAXED, __HIP_MEMORY_SCOPE_AGENT);
            __hip_atomic_fetch_add(dd_done, 1, __ATOMIC_RELEASE, __HIP_MEMORY_SCOPE_AGENT);
        }
        return;
    }

    if (bn >= 64) {
        // ---------------- x-gate GEMM: two step-major 128x128 tiles -------
        const int g = bn - 64;
        const int nc = g & 15;
        const int n0 = nc * 128;
        const int lrA = tid >> 2;                    // 0..127
        const int lcA = (tid & 3) * 8;
        const int w8 = tid >> 6;                     // 0..7
        const int wm8 = (w8 & 3) * 32, wn8 = (w8 >> 2) * 64;

#pragma unroll
        for (int ph = 0; ph < 2; ++ph) {
            const int mt = (ph ? 16 : 0) + (g >> 4);
            const int m0 = mt * 128;
            f32x4 acc[2][4] = {};
            for (int k0 = 0; k0 < 512; k0 += 32) {
                int ma = m0 + lrA;                   // xg row = s*64+b
                int fr = ((ma & 63) << 6) | (ma >> 6);   // fuse row = b*64+s
                uint4 a0 = *(const uint4*)(fuse + (size_t)fr * 512 + k0 + lcA);
                uint4 b0 = *(const uint4*)(Wx_t + (size_t)(n0 + lrA) * 512 + k0 + lcA);
                __syncthreads();
                *(uint4*)&As[lrA][lcA] = a0;
                *(uint4*)&Bs[lrA][lcA] = b0;
                __syncthreads();
                short8 af[2], bf[4];
#pragma unroll
                for (int i = 0; i < 2; ++i) af[i] = *(const short8*)&As[wm8 + i * 16 + l16][quad * 8];
#pragma unroll
                for (int j = 0; j < 4; ++j) bf[j] = *(const short8*)&Bs[wn8 + j * 16 + l16][quad * 8];
#pragma unroll
                for (int i = 0; i < 2; ++i)
#pragma unroll
                    for (int j = 0; j < 4; ++j)
                        acc[i][j] = __builtin_amdgcn_mfma_f32_16x16x32_bf16(af[i], bf[j], acc[i][j], 0, 0, 0);
            }
            float bb[4];
#pragma unroll
            for (int j = 0; j < 4; ++j) bb[j] = bxh[n0 + wn8 + j * 16 + l16];
#pragma unroll
            for (int i = 0; i < 2; ++i) {
                int mbase = m0 + wm8 + i * 16 + quad * 4;
#pragma unroll
                for (int r = 0; r < 4; ++r) {
                    ushort* crow = xg + (size_t)(mbase + r) * 2048;
#pragma unroll
                    for (int j = 0; j < 4; ++j)
                        crow[n0 + wn8 + j * 16 + l16] = f2bf(acc[i][j][r] + bb[j]);
                }
            }
            asm volatile("s_waitcnt vmcnt(0)" ::: "memory");
            __syncthreads();
            if (tid == 0)
                __hip_atomic_store(&xgf[mt * 16 + nc], 1, __ATOMIC_RELAXED,
                                   __HIP_MEMORY_SCOPE_AGENT);
        }
        return;
    }

    // ---------------------------- LSTM block (r16) ----------------------
    __builtin_amdgcn_s_setprio(1);       // latency-critical role: issue pref
    const int i = bn & 15;               // hidden slice (128 n'-rows)
    const int j = bn >> 4;               // batch group (16 batches)
    const int uloc = wv * 4 + quad;      // local hidden unit 0..31

    short8 wfrag[16];
#pragma unroll
    for (int kc = 0; kc < 16; ++kc)
        wfrag[kc] = *(const short8*)(Whr +
            (size_t)(i * 128 + wv * 16 + l16) * 512 + kc * 32 + quad * 8);

    float c = 0.f;

    for (int s = 0; s < 64; ++s) {
        // ---- wait for h(s) [lanes 0..15] and xg tile [lane 16] ----
        if (s > 0) {
            if (tid < 16) {
                const int* f = flags + (j * 16 + tid) * 32;
                while (__hip_atomic_load(f, __ATOMIC_RELAXED,
                                         __HIP_MEMORY_SCOPE_AGENT) < s) {}
            } else if (tid == 16) {
                const int xi = (s >> 1) * 16 + i;
                while (__hip_atomic_load(&xgf[xi], __ATOMIC_RELAXED,
                                         __HIP_MEMORY_SCOPE_AGENT) == 0) {}
            }
            __builtin_amdgcn_s_barrier();
            asm volatile("" ::: "memory");
        } else {
            if (tid == 0) {
                while (__hip_atomic_load(&xgf[i], __ATOMIC_RELAXED,
                                         __HIP_MEMORY_SCOPE_AGENT) == 0) {}
            }
            __builtin_amdgcn_s_barrier();
            asm volatile("" ::: "memory");
        }

        // x-gates: one 8-B load per lane; drained by the staging vmcnt(0).
        const ushort* xp = xg + (size_t)(s * 64 + j * 16 + l16) * 2048
                              + i * 128 + wv * 16 + quad * 4;
        ushort4 xa = *(const ushort4*)xp;

        const ushort* hin = hbuf + (size_t)s * 32768 + j * 8192;
        ushort* hout = hbuf + (size_t)(s + 1) * 32768 + j * 8192;

        // ---- stage 16 KB h-slice into LDS (2 rows per wave, padded) ----
        {
            int r0 = wv * 2;
            __builtin_amdgcn_global_load_lds(
                (const __attribute__((address_space(1))) void*)(hin + (size_t)r0 * 512 + lane * 8),
                (__attribute__((address_space(3))) void*)(hin_s + r0 * 520),
                16, 0, 0);
            __builtin_amdgcn_global_load_lds(
                (const __attribute__((address_space(1))) void*)(hin + (size_t)(r0 + 1) * 512 + lane * 8),
                (__attribute__((address_space(3))) void*)(hin_s + (r0 + 1) * 520),
                16, 0, 0);
        }
        asm volatile("s_waitcnt vmcnt(0)" ::: "memory");
        __builtin_amdgcn_s_barrier();
        asm volatile("" ::: "memory");

        // ---- gates = xg + h @ Wh^T (two interleaved MFMA chains) ----
        f32x4 aA = {bf2f(xa.x), bf2f(xa.y), bf2f(xa.z), bf2f(xa.w)};
        f32x4 aB = {};
#pragma unroll
        for (int kc = 0; kc < 16; kc += 2) {
            short8 h0 = *(const short8*)(hin_s + l16 * 520 + kc * 32 + quad * 8);
            short8 h1 = *(const short8*)(hin_s + l16 * 520 + (kc + 1) * 32 + quad * 8);
            aA = __builtin_amdgcn_mfma_f32_16x16x32_bf16(wfrag[kc], h0, aA, 0, 0, 0);
            aB = __builtin_amdgcn_mfma_f32_16x16x32_bf16(wfrag[kc + 1], h1, aB, 0, 0, 0);
        }

        float gi = sigm(aA[0] + aB[0]);
        float gf = sigm(aA[1] + aB[1]);
        float go = sigm(aA[2] + aB[2]);
        float gg = tanh_fast(aA[3] + aB[3]);
        c = gf * c + gi * gg;
        hstage[l16 * 32 + uloc] = f2bf(go * c);      // no tanh on c (matches ref)

        asm volatile("s_waitcnt lgkmcnt(0)" ::: "memory");
        __builtin_amdgcn_s_barrier();
        asm volatile("" ::: "memory");

        // ---- publish h-slice: 16 rows x 64 B at column i*32 ----
        if (tid < 128) {
            int r = tid >> 3, ch = tid & 7;
            __hip_atomic_store((ull*)(hout + (size_t)r * 512 + i * 32) + ch,
                               ((const ull*)hstage)[tid],
                               __ATOMIC_RELAXED, __HIP_MEMORY_SCOPE_AGENT);
        }
        __syncthreads();                             // drains h stores
        if (tid == 0)
            __hip_atomic_store(&flags[bn * 32], s + 1, __ATOMIC_RELAXED,
                               __HIP_MEMORY_SCOPE_AGENT);
    }

    // -------------------- final head (block 0 only) --------------------
    if (bn == 0) {
        if (tid < 64) {
            while (__hip_atomic_load(&flags[tid * 32], __ATOMIC_RELAXED,
                                     __HIP_MEMORY_SCOPE_AGENT) < 64) {}
        }
        __syncthreads();
        asm volatile("" ::: "memory");
        const ushort* hb64 = hbuf + (size_t)64 * 32768;
        int b = tid & 63, part = tid >> 6;
        const ushort* row = hb64 + (size_t)(b >> 4) * 8192 + (b & 15) * 512;
        float acc = 0.f;
#pragma unroll
        for (int g8 = 0; g8 < 8; ++g8) {
            const ushort* hp = row + part * 64 + g8 * 8;
            const float* wd = W_dec + part * 64 + g8 * 8;
#pragma unroll
            for (int half = 0; half < 2; ++half) {
                ull u = *(const ull*)(hp + half * 4);
                acc += bf2f((ushort)u) * wd[half * 4]
                     + bf2f((ushort)(u >> 16)) * wd[half * 4 + 1]
                     + bf2f((ushort)(u >> 32)) * wd[half * 4 + 2]
                     + bf2f((ushort)(u >> 48)) * wd[half * 4 + 3];
            }
        }
        fred[part][b] = acc;
        __syncthreads();
        if (tid == 0) {                              // wait for dd blocks
            while (__hip_atomic_load(dd_done, __ATOMIC_RELAXED,
                                     __HIP_MEMORY_SCOPE_AGENT) < 64) {}
        }
        __syncthreads();
        asm volatile("" ::: "memory");
        if (tid < 64) {
            float a = 0.f;
#pragma unroll
            for (int p = 0; p < 8; ++p) a += fred[p][tid];
            float gl = __hip_atomic_load(&g_logit[tid], __ATOMIC_RELAXED,
                                         __HIP_MEMORY_SCOPE_AGENT);
            float dl = __hip_atomic_load(&dd_logit[tid], __ATOMIC_RELAXED,
                                         __HIP_MEMORY_SCOPE_AGENT);
            float output = sigm(a + b_dec[0]);
            float gate   = sigm(gl * (1.0f / 64.f) + b_gate[0]);
            float ddp    = sigm(dl + b_dd[0]);
            out[tid] = output * gate + ddp * (1.f - gate);
        }
    }
}

extern "C" void kernel_launch(void* const* d_in, const int* in_sizes, int n_in,
                              void* d_out, int out_size, void* d_ws, size_t ws_size,
                              hipStream_t stream) {
    const float* v_feat   = (const float*)d_in[0];
    const int*   category = (const int*)d_in[1];
    const float* W_enc    = (const float*)d_in[2];
    const float* b_enc    = (const float*)d_in[3];
    const float* Wx       = (const float*)d_in[4];
    const float* bx       = (const float*)d_in[5];
    const float* Wh       = (const float*)d_in[6];
    const float* bh       = (const float*)d_in[7];
    const float* cat_emb  = (const float*)d_in[8];
    const float* W_dec    = (const float*)d_in[9];
    const float* b_dec    = (const float*)d_in[10];
    const float* proto    = (const float*)d_in[11];
    const float* W_dd     = (const float*)d_in[12];
    const float* b_dd     = (const float*)d_in[13];
    const float* W_gate   = (const float*)d_in[14];
    const float* b_gate   = (const float*)d_in[15];
    float* out = (float*)d_out;

    char* ws = (char*)d_ws;
    ushort* xg       = (ushort*)(ws + 0);          // 16 MB
    ushort* fuse     = (ushort*)(ws + 16777216);   // 4 MB
    ushort* Whr      = (ushort*)(ws + 20971520);   // 2 MB
    ushort* Wenc_t   = (ushort*)(ws + 23068672);   // 2 MB
    ushort* Wx_t     = (ushort*)(ws + 25165824);   // 2 MB
    ushort* proto_bf = (ushort*)(ws + 27262976);   // 128 KB
    float*  dots     = (float*)(ws + 27394048);    // 512 KB
    float*  n2       = (float*)(ws + 27918336);    // 16 KB
    float*  gpart    = (float*)(ws + 27934720);    // 16 KB
    float*  p2       = (float*)(ws + 27951104);    // 512 B (20 used)
    int*    dd_done  = (int*)(ws + 27951232);      // 4 B (inside p2 pad)
    float*  bxh      = (float*)(ws + 27951616);    // 8 KB
    int*    flags    = (int*)(ws + 27959808);      // 8 KB (64 x 128B lines)
    float*  dd_logit = (float*)(ws + 27967744);    // 256 B
    float*  g_logit  = (float*)(ws + 27968000);    // 256 B
    ushort* hbuf     = (ushort*)(ws + 27968256);   // 65 x 64 KB rotating h
    int*    xgf      = (int*)(ws + 32228096);      // 2 KB xg tile flags

    k_prep<<<3166, 256, 0, stream>>>(proto, bx, bh, W_enc, Wx, Wh,
                                     proto_bf, bxh, Wenc_t, Wx_t, Whr,
                                     p2, hbuf, flags, dd_done, xgf);

    k_mid<<<320, 256, 0, stream>>>(v_feat, Wenc_t, b_enc, cat_emb, category,
                                   fuse, proto_bf, dots, W_gate, n2, gpart);

    k_lstm_persist<<<384, 512, 0, stream>>>(xg, fuse, Wx_t, bxh, xgf,
                                            Whr, hbuf, flags,
                                            W_dec, b_dec, b_dd, b_gate,
                                            dots, n2, p2, W_dd, gpart,
                                            dd_logit, g_logit, dd_done, out);
}

// Round 11
// 229.121 us; speedup vs baseline: 1.0450x; 1.0450x over previous
//
#include <hip/hip_runtime.h>
#include <cstdint>
#include <cstddef>

// ---------------------------------------------------------------------------
// ASD_RNN round 21: r19 (best, 231.9us) consolidated.
//  - setprio removed (measured null-to-negative, r20).
//  - v_bf16 pre-conversion RESTORED (r20's f32-direct read was a net loss).
//  - Wx/Wh transposes + bxh + hbuf0/flags/xgf zeroing moved from k_prep into
//    k_mid as extra independent blocks (overlap with GEMM1/dot; stream order
//    still guarantees completion before the persistent kernel).
// B=64, S=64, F_IN=2048, H=512, 4H=2048, P2=20.
// ---------------------------------------------------------------------------

typedef __attribute__((ext_vector_type(8))) short short8;
typedef __attribute__((ext_vector_type(4))) float f32x4;
typedef unsigned long long ull;

__device__ __forceinline__ ushort f2bf(float x) {
    uint32_t u = __float_as_uint(x);
    return (ushort)((u + 0x7FFF + ((u >> 16) & 1)) >> 16);   // RNE
}
__device__ __forceinline__ float bf2f(ushort u) {
    return __uint_as_float(((uint32_t)u) << 16);
}
__device__ __forceinline__ float sigm(float x) { return 1.f / (1.f + expf(-x)); }
__device__ __forceinline__ float tanh_fast(float x) { return 2.f / (1.f + expf(-2.f * x)) - 1.f; }

// ---------------------------------------------------------------------------
// k_prep: only what k_mid consumes.
//   [0,4096)      v row convert + n2/gpart rowstats (one pass)
//   [4096,4136)   proto convert
//   [4136,4148)   proto pad rows 20..31
//   [4148,5172)   W_enc transpose
//   [5172]        p2 + dd_done zero
// ---------------------------------------------------------------------------
__global__ __launch_bounds__(256) void k_prep(
    const float* __restrict__ v_feat, const float* __restrict__ proto,
    const float* __restrict__ W_enc, const float* __restrict__ W_gate,
    ushort* __restrict__ v_bf16, ushort* __restrict__ proto_bf,
    ushort* __restrict__ Wenc_t,
    float* __restrict__ n2, float* __restrict__ gpart, float* __restrict__ p2,
    int* __restrict__ dd_done)
{
    __shared__ float ts[32][33];
    const int blk = blockIdx.x;
    const int tid = threadIdx.x;

    if (blk < 4096) {                               // v row convert + stats
        const int bs = blk;
        const float* vr = v_feat + (size_t)bs * 2048;
        float4 x0 = ((const float4*)vr)[tid];
        float4 x1 = ((const float4*)vr)[tid + 256];
        float4 w0 = ((const float4*)W_gate)[tid];
        float4 w1 = ((const float4*)W_gate)[tid + 256];
        ushort4 o0, o1;
        o0.x = f2bf(x0.x); o0.y = f2bf(x0.y); o0.z = f2bf(x0.z); o0.w = f2bf(x0.w);
        o1.x = f2bf(x1.x); o1.y = f2bf(x1.y); o1.z = f2bf(x1.z); o1.w = f2bf(x1.w);
        ((ushort4*)v_bf16)[(size_t)bs * 512 + tid] = o0;
        ((ushort4*)v_bf16)[(size_t)bs * 512 + tid + 256] = o1;
        float a = x0.x * x0.x + x0.y * x0.y + x0.z * x0.z + x0.w * x0.w
                + x1.x * x1.x + x1.y * x1.y + x1.z * x1.z + x1.w * x1.w;
        float g = x0.x * w0.x + x0.y * w0.y + x0.z * w0.z + x0.w * w0.w
                + x1.x * w1.x + x1.y * w1.y + x1.z * w1.z + x1.w * w1.w;
        const int lane = tid & 63, w = tid >> 6;
#pragma unroll
        for (int o = 32; o > 0; o >>= 1) { a += __shfl_down(a, o); g += __shfl_down(g, o); }
        if (lane == 0) { ts[0][w] = a; ts[1][w] = g; }
        __syncthreads();
        if (tid == 0) {
            n2[bs]    = ts[0][0] + ts[0][1] + ts[0][2] + ts[0][3];
            gpart[bs] = ts[1][0] + ts[1][1] + ts[1][2] + ts[1][3];
        }
    } else if (blk < 4136) {                        // proto convert
        int i = (blk - 4096) * 256 + tid;
        float4 v = ((const float4*)proto)[i];
        ushort4 o;
        o.x = f2bf(v.x); o.y = f2bf(v.y); o.z = f2bf(v.z); o.w = f2bf(v.w);
        ((ushort4*)proto_bf)[i] = o;
    } else if (blk < 4148) {                        // proto pad rows 20..31
        int row = 20 + (blk - 4136);
        ushort4 z = {0, 0, 0, 0};
        ((ushort4*)(proto_bf + (size_t)row * 2048))[tid * 2] = z;
        ((ushort4*)(proto_bf + (size_t)row * 2048))[tid * 2 + 1] = z;
    } else if (blk < 5172) {                        // W_enc transpose
        const int t = blk - 4148;
        const int R = 2048, C = 512;
        int tpr = C / 32;
        int cx = t % tpr, cy = t / tpr;
        int r0 = cy * 32, c0 = cx * 32;
        int rr = tid >> 3, cc = (tid & 7) * 4;
        float4 v = *(const float4*)(W_enc + (size_t)(r0 + rr) * C + c0 + cc);
        ts[rr][cc + 0] = v.x; ts[rr][cc + 1] = v.y; ts[rr][cc + 2] = v.z; ts[rr][cc + 3] = v.w;
        __syncthreads();
        ushort4 o;
        o.x = f2bf(ts[cc + 0][rr]);
        o.y = f2bf(ts[cc + 1][rr]);
        o.z = f2bf(ts[cc + 2][rr]);
        o.w = f2bf(ts[cc + 3][rr]);
        int n = c0 + rr;
        *(ushort4*)(Wenc_t + (size_t)n * R + r0 + cc) = o;
    } else {                                        // p2 + dd_done zero
        const int lane = tid & 63, w = tid >> 6;
        for (int p = w; p < 20; p += 4) {
            const float* pr = proto + (size_t)p * 2048;
            float a = 0.f;
#pragma unroll
            for (int i = 0; i < 8; ++i) {
                float4 x = ((const float4*)pr)[i * 64 + lane];
                a += x.x * x.x + x.y * x.y + x.z * x.z + x.w * x.w;
            }
#pragma unroll
            for (int o = 32; o > 0; o >>= 1) a += __shfl_down(a, o);
            if (lane == 0) p2[p] = a;
        }
        if (tid == 0) *dd_done = 0;
    }
}

// ---------------------------------------------------------------------------
// k_mid: GEMM1 (blocks 0..255) + dot (256..319) + persist-only prep moved in:
//   [320,2368)  Wx / Wh transposes (overlap with GEMM1)
//   [2368,2376) bias remap (bxh)
//   [2376,2408) hbuf slot 0 zero
//   [2408]      flags + xgf zero
// ---------------------------------------------------------------------------
__global__ __launch_bounds__(256) void k_mid(
    const ushort* __restrict__ A, const ushort* __restrict__ Bt,
    const float* __restrict__ bias0,
    const float* __restrict__ cat_emb, const int* __restrict__ category,
    ushort* __restrict__ C,
    const ushort* __restrict__ proto_bf, float* __restrict__ dots,
    const float* __restrict__ Wx, const float* __restrict__ Wh,
    const float* __restrict__ bx, const float* __restrict__ bh,
    ushort* __restrict__ Wx_t, ushort* __restrict__ Whr,
    float* __restrict__ bxh, ushort* __restrict__ hbuf,
    int* __restrict__ flags, int* __restrict__ xgf)
{
    __shared__ ushort As[64][40];
    __shared__ ushort Bs[128][40];
    __shared__ float ts[32][33];
    const int tid = threadIdx.x;
    const int lane = tid & 63, w = tid >> 6;
    const int quad = lane >> 4, l16 = lane & 15;
    const int blk = blockIdx.x;

    if (blk >= 2408) {                              // flags + xgf zero
        for (int i = tid; i < 2048; i += 256) flags[i] = 0;
        for (int i = tid; i < 512; i += 256) xgf[i] = 0;
        return;
    }
    if (blk >= 2376) {                              // hbuf slot 0 zero
        ((ull*)hbuf)[(blk - 2376) * 256 + tid] = 0ULL;
        return;
    }
    if (blk >= 2368) {                              // bias remap
        int n = (blk - 2368) * 256 + tid;
        int np = ((n & 511) << 2) | (n >> 9);
        bxh[np] = bx[n] + bh[n];
        return;
    }
    if (blk >= 320) {                               // Wx / Wh transposes
        int t2 = blk - 320;
        const float* in;
        ushort* outp;
        int t;
        if (t2 < 1024) { in = Wx; outp = Wx_t; t = t2; }
        else           { in = Wh; outp = Whr;  t = t2 - 1024; }
        const int R = 512, C = 2048;
        int tpr = C / 32;                           // 64
        int cx = t % tpr, cy = t / tpr;
        int r0 = cy * 32, c0 = cx * 32;
        int rr = tid >> 3, cc = (tid & 7) * 4;
        float4 v = *(const float4*)(in + (size_t)(r0 + rr) * C + c0 + cc);
        ts[rr][cc + 0] = v.x; ts[rr][cc + 1] = v.y; ts[rr][cc + 2] = v.z; ts[rr][cc + 3] = v.w;
        __syncthreads();
        ushort4 o;
        o.x = f2bf(ts[cc + 0][rr]);
        o.y = f2bf(ts[cc + 1][rr]);
        o.z = f2bf(ts[cc + 2][rr]);
        o.w = f2bf(ts[cc + 3][rr]);
        int n = c0 + rr;
        int np = ((n & 511) << 2) | (n >> 9);       // remap
        *(ushort4*)(outp + (size_t)np * R + r0 + cc) = o;
        return;
    }

    if (blk >= 256) {
        // ---------------- dot body (block index blk-256) ----------------
        const int r0 = (blk - 256) * 64 + w * 16;
        f32x4 acc[2] = {};
        const ushort* arow = A + (size_t)(r0 + l16) * 2048 + quad * 8;
        const ushort* b0p = proto_bf + (size_t)l16 * 2048 + quad * 8;
        const ushort* b1p = proto_bf + (size_t)(16 + l16) * 2048 + quad * 8;
#pragma unroll 8
        for (int kk = 0; kk < 64; ++kk) {
            short8 af = *(const short8*)(arow + kk * 32);
            short8 bf0 = *(const short8*)(b0p + kk * 32);
            short8 bf1 = *(const short8*)(b1p + kk * 32);
            acc[0] = __builtin_amdgcn_mfma_f32_16x16x32_bf16(af, bf0, acc[0], 0, 0, 0);
            acc[1] = __builtin_amdgcn_mfma_f32_16x16x32_bf16(af, bf1, acc[1], 0, 0, 0);
        }
#pragma unroll
        for (int t = 0; t < 2; ++t)
#pragma unroll
            for (int r = 0; r < 4; ++r)
                dots[(size_t)(r0 + quad * 4 + r) * 32 + t * 16 + l16] = acc[t][r];
        return;
    }

    // ---------------- GEMM1 tile: m0 = (blk>>2)*64, n0 = (blk&3)*128 -------
    const int m0 = (blk >> 2) * 64, n0 = (blk & 3) * 128;
    const int wm = (w & 1) * 32, wn = (w >> 1) * 64;
    const int K = 2048;

    f32x4 acc[2][4] = {};
    const int lr = tid >> 2;
    const int lc = (tid & 3) * 8;

    for (int k0 = 0; k0 < K; k0 += 32) {
        uint4 a0 = *(const uint4*)(A + (size_t)(m0 + lr) * K + k0 + lc);
        uint4 b0 = *(const uint4*)(Bt + (size_t)(n0 + lr) * K + k0 + lc);
        uint4 b1 = *(const uint4*)(Bt + (size_t)(n0 + 64 + lr) * K + k0 + lc);
        __syncthreads();
        *(uint4*)&As[lr][lc] = a0;
        *(uint4*)&Bs[lr][lc] = b0;
        *(uint4*)&Bs[64 + lr][lc] = b1;
        __syncthreads();
        short8 af[2], bf[4];
#pragma unroll
        for (int i = 0; i < 2; ++i) af[i] = *(const short8*)&As[wm + i * 16 + l16][quad * 8];
#pragma unroll
        for (int j = 0; j < 4; ++j) bf[j] = *(const short8*)&Bs[wn + j * 16 + l16][quad * 8];
#pragma unroll
        for (int i = 0; i < 2; ++i)
#pragma unroll
            for (int j = 0; j < 4; ++j)
                acc[i][j] = __builtin_amdgcn_mfma_f32_16x16x32_bf16(af[i], bf[j], acc[i][j], 0, 0, 0);
    }

#pragma unroll
    for (int i = 0; i < 2; ++i) {
        int mbase = m0 + wm + i * 16 + quad * 4;
#pragma unroll
        for (int r = 0; r < 4; ++r) {
            int m = mbase + r;
            const float* ce = cat_emb + category[m >> 6] * 512;
#pragma unroll
            for (int j = 0; j < 4; ++j) {
                int n = n0 + wn + j * 16 + l16;
                float v = fmaxf(acc[i][j][r] + bias0[n], 0.f) + ce[n];
                C[(size_t)m * 512 + n] = f2bf(v);
            }
        }
    }
}

// ---------------------------------------------------------------------------
// Persistent fused kernel: 384 blocks x 512 threads (r19, no setprio).
//  blocks 0..63   : LSTM (r16 protocol; xg gated by xgf flags).
//  blocks 64..319 : x-gate GEMM, step-major tiles, two phases per block.
//  blocks 320..383: dd logit for batch (bn-320).
// ---------------------------------------------------------------------------
__global__ __launch_bounds__(512, 2) void k_lstm_persist(
    ushort* __restrict__ xg,             // [s][b][n'] bf16 (written by GEMM2 role)
    const ushort* __restrict__ fuse,     // [b*64+s][512] bf16
    const ushort* __restrict__ Wx_t,     // [n'][512] bf16
    const float* __restrict__ bxh,       // [n'] fp32
    int* __restrict__ xgf,               // [32*16] tile flags
    const ushort* __restrict__ Whr,      // [n'=2048][k=512] bf16
    ushort* __restrict__ hbuf,           // 65 slots x 32768 ushorts (slot0 zero)
    int* __restrict__ flags,             // [64*32] zeroed, line-padded
    const float* __restrict__ W_dec, const float* __restrict__ b_dec,
    const float* __restrict__ b_dd, const float* __restrict__ b_gate,
    const float* __restrict__ dots, const float* __restrict__ n2,
    const float* __restrict__ p2, const float* __restrict__ W_dd,
    const float* __restrict__ gpart,
    float* __restrict__ dd_logit, float* __restrict__ g_logit,
    int* __restrict__ dd_done,
    float* __restrict__ out)
{
    __shared__ __align__(16) ushort hin_s[16 * 520];   // LSTM: 16 rows pad 1040B
    __shared__ __align__(16) ushort hstage[512];
    __shared__ float fred[8][64];
    __shared__ __align__(16) ushort As[128][40];       // GEMM role
    __shared__ __align__(16) ushort Bs[128][40];

    const int tid = threadIdx.x;
    const int lane = tid & 63, wv = tid >> 6;
    const int quad = lane >> 4, l16 = lane & 15;
    const int bn = blockIdx.x;

    if (bn >= 320) {
        // ---------------- dd logit for batch b (dots precomputed) --------
        const int b = bn - 320;
        if (tid < 64) {                              // g_logit reduction
            float gp = gpart[b * 64 + tid];
#pragma unroll
            for (int o = 32; o > 0; o >>= 1) gp += __shfl_down(gp, o);
            if (tid == 0)
                __hip_atomic_store(&g_logit[b], gp, __ATOMIC_RELAXED, __HIP_MEMORY_SCOPE_AGENT);
        }
        float acc = 0.f;
        for (int u = tid; u < 1280; u += 512) {
            int s = u / 20, p = u - s * 20;
            int bs = b * 64 + s;
            float d = n2[bs] - 2.f * dots[(size_t)bs * 32 + p] + p2[p];
            acc += logf((d + 1.0f) / (d + 1e-8f)) * W_dd[s * 20 + p];
        }
#pragma unroll
        for (int o = 32; o > 0; o >>= 1) acc += __shfl_down(acc, o);
        if (lane == 0) fred[wv][0] = acc;
        __syncthreads();
        if (tid == 0) {
            float t = 0.f;
#pragma unroll
            for (int p = 0; p < 8; ++p) t += fred[p][0];
            __hip_atomic_store(&dd_logit[b], t, __ATOMIC_RELAXED, __HIP_MEMORY_SCOPE_AGENT);
            __hip_atomic_fetch_add(dd_done, 1, __ATOMIC_RELEASE, __HIP_MEMORY_SCOPE_AGENT);
        }
        return;
    }

    if (bn >= 64) {
        // ---------------- x-gate GEMM: two step-major 128x128 tiles -------
        const int g = bn - 64;
        const int nc = g & 15;
        const int n0 = nc * 128;
        const int lrA = tid >> 2;                    // 0..127
        const int lcA = (tid & 3) * 8;
        const int w8 = tid >> 6;                     // 0..7
        const int wm8 = (w8 & 3) * 32, wn8 = (w8 >> 2) * 64;

#pragma unroll
        for (int ph = 0; ph < 2; ++ph) {
            const int mt = (ph ? 16 : 0) + (g >> 4);
            const int m0 = mt * 128;
            f32x4 acc[2][4] = {};
            for (int k0 = 0; k0 < 512; k0 += 32) {
                int ma = m0 + lrA;                   // xg row = s*64+b
                int fr = ((ma & 63) << 6) | (ma >> 6);   // fuse row = b*64+s
                uint4 a0 = *(const uint4*)(fuse + (size_t)fr * 512 + k0 + lcA);
                uint4 b0 = *(const uint4*)(Wx_t + (size_t)(n0 + lrA) * 512 + k0 + lcA);
                __syncthreads();
                *(uint4*)&As[lrA][lcA] = a0;
                *(uint4*)&Bs[lrA][lcA] = b0;
                __syncthreads();
                short8 af[2], bf[4];
#pragma unroll
                for (int i = 0; i < 2; ++i) af[i] = *(const short8*)&As[wm8 + i * 16 + l16][quad * 8];
#pragma unroll
                for (int j = 0; j < 4; ++j) bf[j] = *(const short8*)&Bs[wn8 + j * 16 + l16][quad * 8];
#pragma unroll
                for (int i = 0; i < 2; ++i)
#pragma unroll
                    for (int j = 0; j < 4; ++j)
                        acc[i][j] = __builtin_amdgcn_mfma_f32_16x16x32_bf16(af[i], bf[j], acc[i][j], 0, 0, 0);
            }
            float bb[4];
#pragma unroll
            for (int j = 0; j < 4; ++j) bb[j] = bxh[n0 + wn8 + j * 16 + l16];
#pragma unroll
            for (int i = 0; i < 2; ++i) {
                int mbase = m0 + wm8 + i * 16 + quad * 4;
#pragma unroll
                for (int r = 0; r < 4; ++r) {
                    ushort* crow = xg + (size_t)(mbase + r) * 2048;
#pragma unroll
                    for (int j = 0; j < 4; ++j)
                        crow[n0 + wn8 + j * 16 + l16] = f2bf(acc[i][j][r] + bb[j]);
                }
            }
            asm volatile("s_waitcnt vmcnt(0)" ::: "memory");
            __syncthreads();
            if (tid == 0)
                __hip_atomic_store(&xgf[mt * 16 + nc], 1, __ATOMIC_RELAXED,
                                   __HIP_MEMORY_SCOPE_AGENT);
        }
        return;
    }

    // ---------------------------- LSTM block (r16) ----------------------
    const int i = bn & 15;               // hidden slice (128 n'-rows)
    const int j = bn >> 4;               // batch group (16 batches)
    const int uloc = wv * 4 + quad;      // local hidden unit 0..31

    short8 wfrag[16];
#pragma unroll
    for (int kc = 0; kc < 16; ++kc)
        wfrag[kc] = *(const short8*)(Whr +
            (size_t)(i * 128 + wv * 16 + l16) * 512 + kc * 32 + quad * 8);

    float c = 0.f;

    for (int s = 0; s < 64; ++s) {
        // ---- wait for h(s) [lanes 0..15] and xg tile [lane 16] ----
        if (s > 0) {
            if (tid < 16) {
                const int* f = flags + (j * 16 + tid) * 32;
                while (__hip_atomic_load(f, __ATOMIC_RELAXED,
                                         __HIP_MEMORY_SCOPE_AGENT) < s) {}
            } else if (tid == 16) {
                const int xi = (s >> 1) * 16 + i;
                while (__hip_atomic_load(&xgf[xi], __ATOMIC_RELAXED,
                                         __HIP_MEMORY_SCOPE_AGENT) == 0) {}
            }
            __builtin_amdgcn_s_barrier();
            asm volatile("" ::: "memory");
        } else {
            if (tid == 0) {
                while (__hip_atomic_load(&xgf[i], __ATOMIC_RELAXED,
                                         __HIP_MEMORY_SCOPE_AGENT) == 0) {}
            }
            __builtin_amdgcn_s_barrier();
            asm volatile("" ::: "memory");
        }

        // x-gates: one 8-B load per lane; drained by the staging vmcnt(0).
        const ushort* xp = xg + (size_t)(s * 64 + j * 16 + l16) * 2048
                              + i * 128 + wv * 16 + quad * 4;
        ushort4 xa = *(const ushort4*)xp;

        const ushort* hin = hbuf + (size_t)s * 32768 + j * 8192;
        ushort* hout = hbuf + (size_t)(s + 1) * 32768 + j * 8192;

        // ---- stage 16 KB h-slice into LDS (2 rows per wave, padded) ----
        {
            int r0 = wv * 2;
            __builtin_amdgcn_global_load_lds(
                (const __attribute__((address_space(1))) void*)(hin + (size_t)r0 * 512 + lane * 8),
                (__attribute__((address_space(3))) void*)(hin_s + r0 * 520),
                16, 0, 0);
            __builtin_amdgcn_global_load_lds(
                (const __attribute__((address_space(1))) void*)(hin + (size_t)(r0 + 1) * 512 + lane * 8),
                (__attribute__((address_space(3))) void*)(hin_s + (r0 + 1) * 520),
                16, 0, 0);
        }
        asm volatile("s_waitcnt vmcnt(0)" ::: "memory");
        __builtin_amdgcn_s_barrier();
        asm volatile("" ::: "memory");

        // ---- gates = xg + h @ Wh^T (two interleaved MFMA chains) ----
        f32x4 aA = {bf2f(xa.x), bf2f(xa.y), bf2f(xa.z), bf2f(xa.w)};
        f32x4 aB = {};
#pragma unroll
        for (int kc = 0; kc < 16; kc += 2) {
            short8 h0 = *(const short8*)(hin_s + l16 * 520 + kc * 32 + quad * 8);
            short8 h1 = *(const short8*)(hin_s + l16 * 520 + (kc + 1) * 32 + quad * 8);
            aA = __builtin_amdgcn_mfma_f32_16x16x32_bf16(wfrag[kc], h0, aA, 0, 0, 0);
            aB = __builtin_amdgcn_mfma_f32_16x16x32_bf16(wfrag[kc + 1], h1, aB, 0, 0, 0);
        }

        float gi = sigm(aA[0] + aB[0]);
        float gf = sigm(aA[1] + aB[1]);
        float go = sigm(aA[2] + aB[2]);
        float gg = tanh_fast(aA[3] + aB[3]);
        c = gf * c + gi * gg;
        hstage[l16 * 32 + uloc] = f2bf(go * c);      // no tanh on c (matches ref)

        asm volatile("s_waitcnt lgkmcnt(0)" ::: "memory");
        __builtin_amdgcn_s_barrier();
        asm volatile("" ::: "memory");

        // ---- publish h-slice: 16 rows x 64 B at column i*32 ----
        if (tid < 128) {
            int r = tid >> 3, ch = tid & 7;
            __hip_atomic_store((ull*)(hout + (size_t)r * 512 + i * 32) + ch,
                               ((const ull*)hstage)[tid],
                               __ATOMIC_RELAXED, __HIP_MEMORY_SCOPE_AGENT);
        }
        __syncthreads();                             // drains h stores
        if (tid == 0)
            __hip_atomic_store(&flags[bn * 32], s + 1, __ATOMIC_RELAXED,
                               __HIP_MEMORY_SCOPE_AGENT);
    }

    // -------------------- final head (block 0 only) --------------------
    if (bn == 0) {
        if (tid < 64) {
            while (__hip_atomic_load(&flags[tid * 32], __ATOMIC_RELAXED,
                                     __HIP_MEMORY_SCOPE_AGENT) < 64) {}
        }
        __syncthreads();
        asm volatile("" ::: "memory");
        const ushort* hb64 = hbuf + (size_t)64 * 32768;
        int b = tid & 63, part = tid >> 6;
        const ushort* row = hb64 + (size_t)(b >> 4) * 8192 + (b & 15) * 512;
        float acc = 0.f;
#pragma unroll
        for (int g8 = 0; g8 < 8; ++g8) {
            const ushort* hp = row + part * 64 + g8 * 8;
            const float* wd = W_dec + part * 64 + g8 * 8;
#pragma unroll
            for (int half = 0; half < 2; ++half) {
                ull u = *(const ull*)(hp + half * 4);
                acc += bf2f((ushort)u) * wd[half * 4]
                     + bf2f((ushort)(u >> 16)) * wd[half * 4 + 1]
                     + bf2f((ushort)(u >> 32)) * wd[half * 4 + 2]
                     + bf2f((ushort)(u >> 48)) * wd[half * 4 + 3];
            }
        }
        fred[part][b] = acc;
        __syncthreads();
        if (tid == 0) {                              // wait for dd blocks
            while (__hip_atomic_load(dd_done, __ATOMIC_RELAXED,
                                     __HIP_MEMORY_SCOPE_AGENT) < 64) {}
        }
        __syncthreads();
        asm volatile("" ::: "memory");
        if (tid < 64) {
            float a = 0.f;
#pragma unroll
            for (int p = 0; p < 8; ++p) a += fred[p][tid];
            float gl = __hip_atomic_load(&g_logit[tid], __ATOMIC_RELAXED,
                                         __HIP_MEMORY_SCOPE_AGENT);
            float dl = __hip_atomic_load(&dd_logit[tid], __ATOMIC_RELAXED,
                                         __HIP_MEMORY_SCOPE_AGENT);
            float output = sigm(a + b_dec[0]);
            float gate   = sigm(gl * (1.0f / 64.f) + b_gate[0]);
            float ddp    = sigm(dl + b_dd[0]);
            out[tid] = output * gate + ddp * (1.f - gate);
        }
    }
}

extern "C" void kernel_launch(void* const* d_in, const int* in_sizes, int n_in,
                              void* d_out, int out_size, void* d_ws, size_t ws_size,
                              hipStream_t stream) {
    const float* v_feat   = (const float*)d_in[0];
    const int*   category = (const int*)d_in[1];
    const float* W_enc    = (const float*)d_in[2];
    const float* b_enc    = (const float*)d_in[3];
    const float* Wx       = (const float*)d_in[4];
    const float* bx       = (const float*)d_in[5];
    const float* Wh       = (const float*)d_in[6];
    const float* bh       = (const float*)d_in[7];
    const float* cat_emb  = (const float*)d_in[8];
    const float* W_dec    = (const float*)d_in[9];
    const float* b_dec    = (const float*)d_in[10];
    const float* proto    = (const float*)d_in[11];
    const float* W_dd     = (const float*)d_in[12];
    const float* b_dd     = (const float*)d_in[13];
    const float* W_gate   = (const float*)d_in[14];
    const float* b_gate   = (const float*)d_in[15];
    float* out = (float*)d_out;

    char* ws = (char*)d_ws;
    ushort* xg       = (ushort*)(ws + 0);          // 16 MB (overlaps v_bf16;
    ushort* v_bf16   = (ushort*)(ws + 0);          //  safe: k_mid completes first)
    ushort* fuse     = (ushort*)(ws + 16777216);   // 4 MB
    ushort* Whr      = (ushort*)(ws + 20971520);   // 2 MB
    ushort* Wenc_t   = (ushort*)(ws + 23068672);   // 2 MB
    ushort* Wx_t     = (ushort*)(ws + 25165824);   // 2 MB
    ushort* proto_bf = (ushort*)(ws + 27262976);   // 128 KB
    float*  dots     = (float*)(ws + 27394048);    // 512 KB
    float*  n2       = (float*)(ws + 27918336);    // 16 KB
    float*  gpart    = (float*)(ws + 27934720);    // 16 KB
    float*  p2       = (float*)(ws + 27951104);    // 512 B (20 used)
    int*    dd_done  = (int*)(ws + 27951232);      // 4 B (inside p2 pad)
    float*  bxh      = (float*)(ws + 27951616);    // 8 KB
    int*    flags    = (int*)(ws + 27959808);      // 8 KB (64 x 128B lines)
    float*  dd_logit = (float*)(ws + 27967744);    // 256 B
    float*  g_logit  = (float*)(ws + 27968000);    // 256 B
    ushort* hbuf     = (ushort*)(ws + 27968256);   // 65 x 64 KB rotating h
    int*    xgf      = (int*)(ws + 32228096);      // 2 KB xg tile flags

    k_prep<<<5173, 256, 0, stream>>>(v_feat, proto, W_enc, W_gate,
                                     v_bf16, proto_bf, Wenc_t,
                                     n2, gpart, p2, dd_done);

    k_mid<<<2409, 256, 0, stream>>>(v_bf16, Wenc_t, b_enc, cat_emb, category,
                                    fuse, proto_bf, dots,
                                    Wx, Wh, bx, bh, Wx_t, Whr, bxh,
                                    hbuf, flags, xgf);

    k_lstm_persist<<<384, 512, 0, stream>>>(xg, fuse, Wx_t, bxh, xgf,
                                            Whr, hbuf, flags,
                                            W_dec, b_dec, b_dd, b_gate,
                                            dots, n2, p2, W_dd, gpart,
                                            dd_logit, g_logit, dd_done, out);
}